// Round 10
// baseline (117.236 us; speedup 1.0000x reference)
//
#include <hip/hip_runtime.h>
#include <hip/hip_bf16.h>
#include <math.h>

#define B_ 32
#define L_ 1024
#define D_ 256

typedef _Float16 half8 __attribute__((ext_vector_type(8)));
typedef __fp16   fp16x2 __attribute__((ext_vector_type(2)));
typedef short    s16x8 __attribute__((ext_vector_type(8)));
typedef float    f32x4 __attribute__((ext_vector_type(4)));

typedef __attribute__((address_space(3))) unsigned int lds_u32;
typedef __attribute__((address_space(1))) unsigned int gbl_u32;

__device__ __forceinline__ void gl_lds16(const void* g, void* l) {
    __builtin_amdgcn_global_load_lds((gbl_u32*)g, (lds_u32*)l, 16, 0, 0);
}

__device__ __forceinline__ unsigned short f2bf(float x) {
    unsigned u = __float_as_uint(x);
    u += 0x7FFFu + ((u >> 16) & 1u);
    return (unsigned short)(u >> 16);
}

__device__ __forceinline__ unsigned short f2h(float x) {
    _Float16 h = (_Float16)x;
    unsigned short u;
    __builtin_memcpy(&u, &h, 2);
    return u;
}

__device__ __forceinline__ unsigned pkrtz(float a, float b) {
    fp16x2 v = __builtin_amdgcn_cvt_pkrtz(a, b);
    unsigned u;
    __builtin_memcpy(&u, &v, 4);
    return u;
}

// ---------------------------------------------------------------------------
// W-prep: Wt[z][n][k] = fp16(W[z][k][n]) via LDS 64x64 tile transpose.
// ---------------------------------------------------------------------------
__global__ __launch_bounds__(256) void wprep_kernel(
    const float* __restrict__ W0, const float* __restrict__ W1,
    const float* __restrict__ W2, unsigned short* __restrict__ Wt)
{
    const int z = blockIdx.z;
    const float* __restrict__ W = (z == 0) ? W0 : (z == 1) ? W1 : W2;
    __shared__ unsigned short T[64][72];
    const int k0 = blockIdx.x << 6, n0 = blockIdx.y << 6;
    const int t = threadIdx.x;
    const int r = t >> 2, c0 = (t & 3) << 4;
    #pragma unroll
    for (int j = 0; j < 16; j += 4) {
        float4 w4 = *(const float4*)(W + (size_t)(k0 + r) * 256 + n0 + c0 + j);
        T[c0 + j + 0][r] = f2h(w4.x);
        T[c0 + j + 1][r] = f2h(w4.y);
        T[c0 + j + 2][r] = f2h(w4.z);
        T[c0 + j + 3][r] = f2h(w4.w);
    }
    __syncthreads();
    const int n = t >> 2, kc = (t & 3) << 4;
    unsigned short* dst = Wt + ((size_t)z << 16) + (size_t)(n0 + n) * 256 + k0 + kc;
    *(uint4*)(dst + 0) = *(const uint4*)&T[n][kc + 0];
    *(uint4*)(dst + 8) = *(const uint4*)&T[n][kc + 8];
}

// ---------------------------------------------------------------------------
// Projection GEMM, fp16 MFMA 16x16x32. C[M=32768,256] = A @ W.
// BM=128, BN=128 (grid y=2), BK=64, 4 waves 2x2, wave tile 64x64.
// Double-buffered LDS (64 KB). A path T14-split. B via gl_lds pre-swizzled.
// z<2: store fp16 row-major. z=2: LDS-transpose -> Vt bf16 [b][d][k].
// ---------------------------------------------------------------------------
__global__ __launch_bounds__(256) void proj_mfma_kernel(
    const float* __restrict__ A0, const float* __restrict__ A1,
    const float* __restrict__ A2, const unsigned short* __restrict__ Wt,
    unsigned short* __restrict__ Qh, unsigned short* __restrict__ Kh,
    unsigned short* __restrict__ Vt)
{
    __shared__ unsigned short SMEM[32768];   // 64 KB
    unsigned short* Asm = SMEM;              // [buf][128*64], buf stride 8192 halves
    unsigned short* Bsm = SMEM + 16384;

    const int z = blockIdx.z;
    const float* __restrict__ A = (z == 0) ? A0 : (z == 1) ? A1 : A2;
    const int bm = blockIdx.x << 7, bn = blockIdx.y << 7;
    const int t = threadIdx.x, lane = t & 63, w = t >> 6;
    const int wm = (w >> 1) << 6, wn = (w & 1) << 6;

    const float* __restrict__ Ag = A + (size_t)bm * 256;
    const unsigned short* __restrict__ Bg = Wt + ((size_t)z << 16) + (size_t)bn * 256;

    f32x4 acc[4][4];
    const f32x4 z4 = {0.f, 0.f, 0.f, 0.f};
    #pragma unroll
    for (int mi = 0; mi < 4; ++mi)
        #pragma unroll
        for (int ni = 0; ni < 4; ++ni) acc[mi][ni] = z4;

    float4 a_reg[8];

    auto loadA = [&](int it) {
        #pragma unroll
        for (int i = 0; i < 8; ++i) {
            int r  = (t >> 4) + (i << 4);
            int c4 = t & 15;
            a_reg[i] = *(const float4*)(Ag + (size_t)r * 256 + (it << 6) + (c4 << 2));
        }
    };
    auto writeA = [&](int buf) {
        #pragma unroll
        for (int i = 0; i < 8; ++i) {
            int r  = (t >> 4) + (i << 4);
            int c4 = t & 15;
            unsigned h01 = pkrtz(a_reg[i].x, a_reg[i].y);
            unsigned h23 = pkrtz(a_reg[i].z, a_reg[i].w);
            int cs = (c4 >> 1) ^ (r & 7);
            uint2 d2; d2.x = h01; d2.y = h23;
            *(uint2*)&Asm[(buf << 13) + (r << 6) + (cs << 3) + ((c4 & 1) << 2)] = d2;
        }
    };
    auto stageB = [&](int buf, int it) {
        #pragma unroll
        for (int rr = 0; rr < 4; ++rr) {
            int o = (rr << 8) + t;
            int r = o >> 3, c = o & 7;
            int cs = c ^ (r & 7);
            gl_lds16(Bg + (size_t)r * 256 + (it << 6) + (cs << 3),
                     &Bsm[(buf << 13) + (o << 3)]);
        }
    };
    auto compute = [&](int buf) {
        #pragma unroll
        for (int kc = 0; kc < 2; ++kc) {
            half8 af[4], bfr[4];
            #pragma unroll
            for (int mi = 0; mi < 4; ++mi) {
                int m = wm + (mi << 4) + (lane & 15);
                int cs = ((kc << 2) + (lane >> 4)) ^ (m & 7);
                af[mi] = *(const half8*)&Asm[(buf << 13) + (m << 6) + (cs << 3)];
            }
            #pragma unroll
            for (int ni = 0; ni < 4; ++ni) {
                int n = wn + (ni << 4) + (lane & 15);
                int cs = ((kc << 2) + (lane >> 4)) ^ (n & 7);
                bfr[ni] = *(const half8*)&Bsm[(buf << 13) + (n << 6) + (cs << 3)];
            }
            #pragma unroll
            for (int mi = 0; mi < 4; ++mi)
                #pragma unroll
                for (int ni = 0; ni < 4; ++ni)
                    acc[mi][ni] = __builtin_amdgcn_mfma_f32_16x16x32_f16(
                        af[mi], bfr[ni], acc[mi][ni], 0, 0, 0);
        }
    };

    loadA(0);
    writeA(0);
    stageB(0, 0);
    loadA(1);
    __syncthreads();

    for (int it = 0; it < 4; ++it) {
        const int buf = it & 1;
        if (it < 3) {
            stageB(buf ^ 1, it + 1);
            writeA(buf ^ 1);
            if (it < 2) loadA(it + 2);
        }
        compute(buf);
        __syncthreads();
    }

    if (z < 2) {
        unsigned short* __restrict__ C = (z == 0) ? Qh : Kh;
        #pragma unroll
        for (int mi = 0; mi < 4; ++mi) {
            int q = bm + wm + (mi << 4) + ((lane >> 4) << 2);
            #pragma unroll
            for (int ni = 0; ni < 4; ++ni) {
                int col = bn + wn + (ni << 4) + (lane & 15);
                #pragma unroll
                for (int r = 0; r < 4; ++r)
                    C[(size_t)(q + r) * 256 + col] = f2h(acc[mi][ni][r]);
            }
        }
    } else {
        __syncthreads();
        unsigned short (*Tt)[144] = (unsigned short(*)[144])SMEM;
        #pragma unroll
        for (int mi = 0; mi < 4; ++mi) {
            #pragma unroll
            for (int ni = 0; ni < 4; ++ni) {
                int n  = wn + (ni << 4) + (lane & 15);
                int m0 = wm + (mi << 4) + ((lane >> 4) << 2);
                ushort4 v;
                v.x = f2bf(acc[mi][ni][0]);
                v.y = f2bf(acc[mi][ni][1]);
                v.z = f2bf(acc[mi][ni][2]);
                v.w = f2bf(acc[mi][ni][3]);
                *(ushort4*)&Tt[n][m0] = v;
            }
        }
        __syncthreads();
        const int bb = bm >> 10, kin = bm & 1023;
        const int dr = t >> 1, cb = (t & 1) << 6;
        unsigned short* dst = Vt + ((size_t)bb * 256 + bn + dr) * 1024 + kin + cb;
        #pragma unroll
        for (int j = 0; j < 8; ++j)
            *(uint4*)(dst + (j << 3)) = *(const uint4*)&Tt[dr][cb + (j << 3)];
    }
}

// ---------------------------------------------------------------------------
// Fused flash attention, QBLK=128, KB=128, 256 blocks (1/CU), 512 threads.
// Single-buffered Ks[128][256] (64KB) + Vs[256][128] (64KB) + Ps[128][128]
// (32KB) = 160 KB LDS exactly. Per k-tile (8 tiles):
//   [stageV(kt) | S(kt) on Ks | exp/P | barrier B (drains V; P visible) |
//    stageK(kt+1) | PV(kt) | barrier A (drains K; Vs/Ps free)]
// Each stage is covered by a 64-MFMA/wave compute phase (round-7 schedule).
// S waves 4(M)x2(N): 32q x 64k. PV waves 2(M)x4(N): 64q x 64d, 4 k-chunks.
// XCD decode: 8 q-tiles of a batch share f%8 -> 4 batches/XCD L2-resident
// (round-9 measured: FETCH = compulsory only).
// ---------------------------------------------------------------------------
__global__ __launch_bounds__(512, 2) void fused_attn_kernel(
    const unsigned short* __restrict__ Qh, const unsigned short* __restrict__ Kh,
    const unsigned short* __restrict__ Vt, const int* __restrict__ mask,
    float* __restrict__ Out)
{
    __shared__ unsigned short Ks[128 * 256];  // 64 KB fp16, 32 chunks/row
    __shared__ unsigned short Vs[256 * 128];  // 64 KB bf16, 16 chunks/row
    __shared__ unsigned short Ps[128 * 128];  // 32 KB bf16, 16 chunks/row
    float* lredp = (float*)Ps;                // overlay, used after the loop

    // XCD-aware decode: f = xcd + 8*qtile + 64*batchgroup
    const int f  = blockIdx.x;
    const int b  = (f & 7) + ((f >> 6) << 3);
    const int q0 = ((f >> 3) & 7) << 7;
    const size_t bL = (size_t)b * L_;
    const int t = threadIdx.x, lane = t & 63, w = t >> 6;
    const int wm_s = (w >> 1) << 5, wn_s = (w & 1) << 6;   // S: 4x2, 32q x 64k
    const int wm_v = (w >> 2) << 6, wn_v = (w & 3) << 6;   // PV: 2x4, 64q x 64d

    const unsigned short* __restrict__ Kb = Kh + (bL << 8);
    const unsigned short* __restrict__ Vb = Vt + (bL << 8);

    auto stageK = [&](int kt) {
        #pragma unroll
        for (int i = 0; i < 8; ++i) {
            int o = (i << 9) + t;            // 0..4095 chunks of 8 halves
            int r = o >> 5, c = o & 31;
            int cs = (c & 24) | ((c & 7) ^ (r & 7));
            gl_lds16(Kb + (size_t)((kt << 7) + r) * 256 + (cs << 3), &Ks[o << 3]);
        }
    };
    auto stageV = [&](int kt) {
        #pragma unroll
        for (int i = 0; i < 8; ++i) {
            int o = (i << 9) + t;            // 0..4095
            int d = o >> 4, c = o & 15;
            int cs = (c & 8) | ((c & 7) ^ (d & 7));
            gl_lds16(Vb + ((size_t)d << 10) + (kt << 7) + (cs << 3), &Vs[o << 3]);
        }
    };

    // prologue: stage tile 0, load Q fragments + mask into registers
    stageK(0);
    stageV(0);

    half8 qf[2][8];
    #pragma unroll
    for (int mi = 0; mi < 2; ++mi) {
        int m = wm_s + (mi << 4) + (lane & 15);
        const unsigned short* qp = Qh + ((bL + q0 + m) << 8) + ((lane >> 4) << 3);
        #pragma unroll
        for (int kc = 0; kc < 8; ++kc)
            qf[mi][kc] = *(const half8*)(qp + (kc << 5));
    }
    int mv[2][4];
    #pragma unroll
    for (int mi = 0; mi < 2; ++mi)
        #pragma unroll
        for (int r = 0; r < 4; ++r)
            mv[mi][r] = mask[bL + q0 + wm_s + (mi << 4) + ((lane >> 4) << 2) + r];

    f32x4 o_acc[4][4];
    const f32x4 z4 = {0.f, 0.f, 0.f, 0.f};
    #pragma unroll
    for (int mi = 0; mi < 4; ++mi)
        #pragma unroll
        for (int ni = 0; ni < 4; ++ni) o_acc[mi][ni] = z4;
    float lacc[2][4] = {};

    __syncthreads();   // tile 0 staged (vmcnt drained)

    for (int kt = 0; kt < 8; ++kt) {
        if (kt > 0) stageV(kt);   // Vs freed at barrier A of kt-1; covered by S

        // ---- S = Q . K^T (wave tile 32x64), Q in regs ----
        f32x4 accs[2][4];
        #pragma unroll
        for (int mi = 0; mi < 2; ++mi)
            #pragma unroll
            for (int ni = 0; ni < 4; ++ni) accs[mi][ni] = z4;
        #pragma unroll
        for (int kc = 0; kc < 8; ++kc) {
            int kb = (kc >> 1) << 6, cc = ((kc & 1) << 2) + (lane >> 4);
            half8 bfr[4];
            #pragma unroll
            for (int ni = 0; ni < 4; ++ni) {
                int n = wn_s + (ni << 4) + (lane & 15);
                bfr[ni] = *(const half8*)&Ks[(n << 8) + kb + ((cc ^ (n & 7)) << 3)];
            }
            #pragma unroll
            for (int mi = 0; mi < 2; ++mi)
                #pragma unroll
                for (int ni = 0; ni < 4; ++ni)
                    accs[mi][ni] = __builtin_amdgcn_mfma_f32_16x16x32_f16(
                        qf[mi][kc], bfr[ni], accs[mi][ni], 0, 0, 0);
        }

        // ---- P = exp(S) (mask -> 1), bf16 to swizzled LDS, accumulate l ----
        #pragma unroll
        for (int mi = 0; mi < 2; ++mi) {
            int qrow = wm_s + (mi << 4) + ((lane >> 4) << 2);
            #pragma unroll
            for (int ni = 0; ni < 4; ++ni) {
                int kl = wn_s + (ni << 4) + (lane & 15);
                int ch = kl >> 3, lo = kl & 7;
                #pragma unroll
                for (int r = 0; r < 4; ++r) {
                    int q = qrow + r;
                    float p = mv[mi][r] ? __expf(accs[mi][ni][r]) : 1.0f;
                    int cs = (ch & 8) | ((ch & 7) ^ (q & 7));
                    Ps[(q << 7) + (cs << 3) + lo] = f2bf(p);
                    lacc[mi][r] += p;
                }
            }
        }
        __syncthreads();   // barrier B: V(kt) drained; P visible; Ks reads done

        if (kt < 7) stageK(kt + 1);   // covered by PV phase

        // ---- O += P . V (wave tile 64q x 64d, k = 128) ----
        #pragma unroll
        for (int kc2 = 0; kc2 < 4; ++kc2) {
            s16x8 pa[4], vb[4];
            int cc = (kc2 << 2) + (lane >> 4);
            #pragma unroll
            for (int mi = 0; mi < 4; ++mi) {
                int m = wm_v + (mi << 4) + (lane & 15);
                int cs = (cc & 8) | ((cc & 7) ^ (m & 7));
                pa[mi] = *(const s16x8*)&Ps[(m << 7) + (cs << 3)];
            }
            #pragma unroll
            for (int ni = 0; ni < 4; ++ni) {
                int n = wn_v + (ni << 4) + (lane & 15);
                int cs = (cc & 8) | ((cc & 7) ^ (n & 7));
                vb[ni] = *(const s16x8*)&Vs[(n << 7) + (cs << 3)];
            }
            #pragma unroll
            for (int mi = 0; mi < 4; ++mi)
                #pragma unroll
                for (int ni = 0; ni < 4; ++ni)
                    o_acc[mi][ni] = __builtin_amdgcn_mfma_f32_16x16x32_bf16(
                        pa[mi], vb[ni], o_acc[mi][ni], 0, 0, 0);
        }
        __syncthreads();   // barrier A: K(kt+1) drained; Vs/Ps reads done
    }

    // ---- l reduction (Ps memory reused as lred[128][2]) ----
    #pragma unroll
    for (int mi = 0; mi < 2; ++mi)
        #pragma unroll
        for (int r = 0; r < 4; ++r) {
            float v = lacc[mi][r];
            v += __shfl_xor(v, 1);
            v += __shfl_xor(v, 2);
            v += __shfl_xor(v, 4);
            v += __shfl_xor(v, 8);
            if ((lane & 15) == 0)
                lredp[((wm_s + (mi << 4) + ((lane >> 4) << 2) + r) << 1) + (w & 1)] = v;
        }
    __syncthreads();

    // ---- epilogue: Out = O / l ----
    #pragma unroll
    for (int mi = 0; mi < 4; ++mi) {
        #pragma unroll
        for (int rr = 0; rr < 4; ++rr) {
            int q = wm_v + (mi << 4) + ((lane >> 4) << 2) + rr;
            float inv = 1.0f / (lredp[q << 1] + lredp[(q << 1) + 1]);
            #pragma unroll
            for (int ni = 0; ni < 4; ++ni) {
                int d = wn_v + (ni << 4) + (lane & 15);
                Out[((bL + q0 + q) << 8) + d] = o_acc[mi][ni][rr] * inv;
            }
        }
    }
}

extern "C" void kernel_launch(void* const* d_in, const int* in_sizes, int n_in,
                              void* d_out, int out_size, void* d_ws, size_t ws_size,
                              hipStream_t stream) {
    const float* rq = (const float*)d_in[0];
    const float* rk = (const float*)d_in[1];
    const float* rv = (const float*)d_in[2];
    const int*   vm = (const int*)d_in[3];
    const float* WQ = (const float*)d_in[4];
    const float* WK = (const float*)d_in[5];
    const float* WV = (const float*)d_in[6];
    float* out = (float*)d_out;

    char* ws = (char*)d_ws;
    unsigned short* Qh = (unsigned short*)(ws);                          // 16 MB fp16 [b*L][D]
    unsigned short* Kh = (unsigned short*)(ws + ((size_t)16 << 20));     // 16 MB fp16 [b*L][D]
    unsigned short* Vt = (unsigned short*)(ws + ((size_t)32 << 20));     // 16 MB bf16 [b][D][LK]
    unsigned short* Wt = (unsigned short*)(ws + ((size_t)48 << 20));     // 384 KB fp16 [3][256][256]

    dim3 wg(4, 4, 3);
    wprep_kernel<<<wg, 256, 0, stream>>>(WQ, WK, WV, Wt);

    dim3 pg(256, 2, 3);
    proj_mfma_kernel<<<pg, 256, 0, stream>>>(rq, rk, rv, Wt, Qh, Kh, Vt);

    fused_attn_kernel<<<256, 512, 0, stream>>>(Qh, Kh, Vt, vm, out);
}

// Round 11
// 91.505 us; speedup vs baseline: 1.2812x; 1.2812x over previous
//
#include <hip/hip_runtime.h>
#include <hip/hip_bf16.h>
#include <math.h>

#define B_ 32
#define L_ 1024
#define D_ 256

typedef _Float16 half8 __attribute__((ext_vector_type(8)));
typedef __fp16   fp16x2 __attribute__((ext_vector_type(2)));
typedef short    s16x8 __attribute__((ext_vector_type(8)));
typedef float    f32x4 __attribute__((ext_vector_type(4)));

typedef __attribute__((address_space(3))) unsigned int lds_u32;
typedef __attribute__((address_space(1))) unsigned int gbl_u32;

__device__ __forceinline__ void gl_lds16(const void* g, void* l) {
    __builtin_amdgcn_global_load_lds((gbl_u32*)g, (lds_u32*)l, 16, 0, 0);
}

__device__ __forceinline__ unsigned short f2bf(float x) {
    unsigned u = __float_as_uint(x);
    u += 0x7FFFu + ((u >> 16) & 1u);
    return (unsigned short)(u >> 16);
}

__device__ __forceinline__ unsigned short f2h(float x) {
    _Float16 h = (_Float16)x;
    unsigned short u;
    __builtin_memcpy(&u, &h, 2);
    return u;
}

__device__ __forceinline__ unsigned pkrtz(float a, float b) {
    fp16x2 v = __builtin_amdgcn_cvt_pkrtz(a, b);
    unsigned u;
    __builtin_memcpy(&u, &v, 4);
    return u;
}

// ---------------------------------------------------------------------------
// W-prep: Wt[z][n][k] = fp16(W[z][k][n]) via LDS 64x64 tile transpose.
// ---------------------------------------------------------------------------
__global__ __launch_bounds__(256) void wprep_kernel(
    const float* __restrict__ W0, const float* __restrict__ W1,
    const float* __restrict__ W2, unsigned short* __restrict__ Wt)
{
    const int z = blockIdx.z;
    const float* __restrict__ W = (z == 0) ? W0 : (z == 1) ? W1 : W2;
    __shared__ unsigned short T[64][72];
    const int k0 = blockIdx.x << 6, n0 = blockIdx.y << 6;
    const int t = threadIdx.x;
    const int r = t >> 2, c0 = (t & 3) << 4;
    #pragma unroll
    for (int j = 0; j < 16; j += 4) {
        float4 w4 = *(const float4*)(W + (size_t)(k0 + r) * 256 + n0 + c0 + j);
        T[c0 + j + 0][r] = f2h(w4.x);
        T[c0 + j + 1][r] = f2h(w4.y);
        T[c0 + j + 2][r] = f2h(w4.z);
        T[c0 + j + 3][r] = f2h(w4.w);
    }
    __syncthreads();
    const int n = t >> 2, kc = (t & 3) << 4;
    unsigned short* dst = Wt + ((size_t)z << 16) + (size_t)(n0 + n) * 256 + k0 + kc;
    *(uint4*)(dst + 0) = *(const uint4*)&T[n][kc + 0];
    *(uint4*)(dst + 8) = *(const uint4*)&T[n][kc + 8];
}

// ---------------------------------------------------------------------------
// Projection GEMM, fp16 MFMA 16x16x32. C[M=32768,256] = A @ W.
// BM=128, BN=128 (grid y=2), BK=64, 4 waves 2x2, wave tile 64x64.
// Double-buffered LDS (64 KB). A path T14-split. B via gl_lds pre-swizzled.
// z<2: store fp16 row-major. z=2: LDS-transpose -> Vt bf16 [b][d][k].
// ---------------------------------------------------------------------------
__global__ __launch_bounds__(256) void proj_mfma_kernel(
    const float* __restrict__ A0, const float* __restrict__ A1,
    const float* __restrict__ A2, const unsigned short* __restrict__ Wt,
    unsigned short* __restrict__ Qh, unsigned short* __restrict__ Kh,
    unsigned short* __restrict__ Vt)
{
    __shared__ unsigned short SMEM[32768];   // 64 KB
    unsigned short* Asm = SMEM;              // [buf][128*64], buf stride 8192 halves
    unsigned short* Bsm = SMEM + 16384;

    const int z = blockIdx.z;
    const float* __restrict__ A = (z == 0) ? A0 : (z == 1) ? A1 : A2;
    const int bm = blockIdx.x << 7, bn = blockIdx.y << 7;
    const int t = threadIdx.x, lane = t & 63, w = t >> 6;
    const int wm = (w >> 1) << 6, wn = (w & 1) << 6;

    const float* __restrict__ Ag = A + (size_t)bm * 256;
    const unsigned short* __restrict__ Bg = Wt + ((size_t)z << 16) + (size_t)bn * 256;

    f32x4 acc[4][4];
    const f32x4 z4 = {0.f, 0.f, 0.f, 0.f};
    #pragma unroll
    for (int mi = 0; mi < 4; ++mi)
        #pragma unroll
        for (int ni = 0; ni < 4; ++ni) acc[mi][ni] = z4;

    float4 a_reg[8];

    auto loadA = [&](int it) {
        #pragma unroll
        for (int i = 0; i < 8; ++i) {
            int r  = (t >> 4) + (i << 4);
            int c4 = t & 15;
            a_reg[i] = *(const float4*)(Ag + (size_t)r * 256 + (it << 6) + (c4 << 2));
        }
    };
    auto writeA = [&](int buf) {
        #pragma unroll
        for (int i = 0; i < 8; ++i) {
            int r  = (t >> 4) + (i << 4);
            int c4 = t & 15;
            unsigned h01 = pkrtz(a_reg[i].x, a_reg[i].y);
            unsigned h23 = pkrtz(a_reg[i].z, a_reg[i].w);
            int cs = (c4 >> 1) ^ (r & 7);
            uint2 d2; d2.x = h01; d2.y = h23;
            *(uint2*)&Asm[(buf << 13) + (r << 6) + (cs << 3) + ((c4 & 1) << 2)] = d2;
        }
    };
    auto stageB = [&](int buf, int it) {
        #pragma unroll
        for (int rr = 0; rr < 4; ++rr) {
            int o = (rr << 8) + t;
            int r = o >> 3, c = o & 7;
            int cs = c ^ (r & 7);
            gl_lds16(Bg + (size_t)r * 256 + (it << 6) + (cs << 3),
                     &Bsm[(buf << 13) + (o << 3)]);
        }
    };
    auto compute = [&](int buf) {
        #pragma unroll
        for (int kc = 0; kc < 2; ++kc) {
            half8 af[4], bfr[4];
            #pragma unroll
            for (int mi = 0; mi < 4; ++mi) {
                int m = wm + (mi << 4) + (lane & 15);
                int cs = ((kc << 2) + (lane >> 4)) ^ (m & 7);
                af[mi] = *(const half8*)&Asm[(buf << 13) + (m << 6) + (cs << 3)];
            }
            #pragma unroll
            for (int ni = 0; ni < 4; ++ni) {
                int n = wn + (ni << 4) + (lane & 15);
                int cs = ((kc << 2) + (lane >> 4)) ^ (n & 7);
                bfr[ni] = *(const half8*)&Bsm[(buf << 13) + (n << 6) + (cs << 3)];
            }
            #pragma unroll
            for (int mi = 0; mi < 4; ++mi)
                #pragma unroll
                for (int ni = 0; ni < 4; ++ni)
                    acc[mi][ni] = __builtin_amdgcn_mfma_f32_16x16x32_f16(
                        af[mi], bfr[ni], acc[mi][ni], 0, 0, 0);
        }
    };

    loadA(0);
    writeA(0);
    stageB(0, 0);
    loadA(1);
    __syncthreads();

    for (int it = 0; it < 4; ++it) {
        const int buf = it & 1;
        if (it < 3) {
            stageB(buf ^ 1, it + 1);
            writeA(buf ^ 1);
            if (it < 2) loadA(it + 2);
        }
        compute(buf);
        __syncthreads();
    }

    if (z < 2) {
        unsigned short* __restrict__ C = (z == 0) ? Qh : Kh;
        #pragma unroll
        for (int mi = 0; mi < 4; ++mi) {
            int q = bm + wm + (mi << 4) + ((lane >> 4) << 2);
            #pragma unroll
            for (int ni = 0; ni < 4; ++ni) {
                int col = bn + wn + (ni << 4) + (lane & 15);
                #pragma unroll
                for (int r = 0; r < 4; ++r)
                    C[(size_t)(q + r) * 256 + col] = f2h(acc[mi][ni][r]);
            }
        }
    } else {
        __syncthreads();
        unsigned short (*Tt)[144] = (unsigned short(*)[144])SMEM;
        #pragma unroll
        for (int mi = 0; mi < 4; ++mi) {
            #pragma unroll
            for (int ni = 0; ni < 4; ++ni) {
                int n  = wn + (ni << 4) + (lane & 15);
                int m0 = wm + (mi << 4) + ((lane >> 4) << 2);
                ushort4 v;
                v.x = f2bf(acc[mi][ni][0]);
                v.y = f2bf(acc[mi][ni][1]);
                v.z = f2bf(acc[mi][ni][2]);
                v.w = f2bf(acc[mi][ni][3]);
                *(ushort4*)&Tt[n][m0] = v;
            }
        }
        __syncthreads();
        const int bb = bm >> 10, kin = bm & 1023;
        const int dr = t >> 1, cb = (t & 1) << 6;
        unsigned short* dst = Vt + ((size_t)bb * 256 + bn + dr) * 1024 + kin + cb;
        #pragma unroll
        for (int j = 0; j < 8; ++j)
            *(uint4*)(dst + (j << 3)) = *(const uint4*)&Tt[dr][cb + (j << 3)];
    }
}

// ---------------------------------------------------------------------------
// Fused flash attention, QBLK=128, KB=64, 256 blocks (1/CU), 1024 threads
// (16 waves = 4 waves/SIMD for latency hiding). Round-9 schedule:
// double-buffered K [2][64][256] + V [2][256][64] + XOR-swizzled Ps [128][64]
// = 144 KB LDS. Per k-tile:
//   [stageV(kt+1) | S(kt) on Ks[cur] | exp/P | barrier B |
//    stageK(kt+1) | PV(kt) on Vs[cur],Ps | barrier A]
// S waves 8(M)x2(N): 16q x 32k, Q in regs. PV waves 4(M)x4(N): 32q x 64d.
// XCD decode: 8 q-tiles of a batch share f%8 -> 4 batches/XCD L2-resident.
// ---------------------------------------------------------------------------
__global__ __launch_bounds__(1024, 4) void fused_attn_kernel(
    const unsigned short* __restrict__ Qh, const unsigned short* __restrict__ Kh,
    const unsigned short* __restrict__ Vt, const int* __restrict__ mask,
    float* __restrict__ Out)
{
    __shared__ unsigned short Ks[2][16384];  // [64][256] halves x2, 64 KB
    __shared__ unsigned short Vs[2][16384];  // [256][64] halves x2, 64 KB
    __shared__ unsigned short Ps[128 * 64];  // 16 KB bf16, XOR-swizzled chunks
    float* lredp = (float*)Ps;               // overlay, used after the loop

    // XCD-aware decode: f = xcd + 8*qtile + 64*batchgroup
    const int f  = blockIdx.x;
    const int b  = (f & 7) + ((f >> 6) << 3);
    const int q0 = ((f >> 3) & 7) << 7;
    const size_t bL = (size_t)b * L_;
    const int t = threadIdx.x, lane = t & 63, w = t >> 6;
    const int wm_s = (w >> 1) << 4, wn_s = (w & 1) << 5;   // S: 8x2, 16q x 32k
    const int wm_v = (w >> 2) << 5, wn_v = (w & 3) << 6;   // PV: 4x4, 32q x 64d

    const unsigned short* __restrict__ Kb = Kh + (bL << 8);
    const unsigned short* __restrict__ Vb = Vt + (bL << 8);

    auto stageK = [&](int buf, int kt) {
        #pragma unroll
        for (int i = 0; i < 2; ++i) {
            int o = (i << 10) + t;           // 0..2047 chunks of 8 halves
            int r = o >> 5, c = o & 31;
            int cs = (c & 24) | ((c & 7) ^ (r & 7));
            gl_lds16(Kb + (size_t)((kt << 6) + r) * 256 + (cs << 3), &Ks[buf][o << 3]);
        }
    };
    auto stageV = [&](int buf, int kt) {
        #pragma unroll
        for (int i = 0; i < 2; ++i) {
            int o = (i << 10) + t;           // 0..2047
            int d = o >> 3, c = o & 7;
            int cs = c ^ (d & 7);
            gl_lds16(Vb + ((size_t)d << 10) + (kt << 6) + (cs << 3), &Vs[buf][o << 3]);
        }
    };

    // prologue: stage tile 0, load Q fragments + mask into registers
    stageK(0, 0);
    stageV(0, 0);

    half8 qf[8];
    {
        int m = wm_s + (lane & 15);
        const unsigned short* qp = Qh + ((bL + q0 + m) << 8) + ((lane >> 4) << 3);
        #pragma unroll
        for (int kc = 0; kc < 8; ++kc)
            qf[kc] = *(const half8*)(qp + (kc << 5));
    }
    int mv[4];
    {
        int qrow = wm_s + ((lane >> 4) << 2);
        #pragma unroll
        for (int r = 0; r < 4; ++r) mv[r] = mask[bL + q0 + qrow + r];
    }

    f32x4 o_acc[2][4];
    const f32x4 z4 = {0.f, 0.f, 0.f, 0.f};
    #pragma unroll
    for (int mi = 0; mi < 2; ++mi)
        #pragma unroll
        for (int ni = 0; ni < 4; ++ni) o_acc[mi][ni] = z4;
    float lacc[4] = {};

    __syncthreads();   // tile 0 staged (vmcnt drained)

    for (int kt = 0; kt < 16; ++kt) {
        const int cur = kt & 1;
        if (kt < 15) stageV(cur ^ 1, kt + 1);   // covered by S-phase

        // ---- S = Q . K^T (wave tile 16q x 32k), Q in regs ----
        f32x4 accs[2];
        accs[0] = z4; accs[1] = z4;
        #pragma unroll
        for (int kc = 0; kc < 8; ++kc) {
            int kb = (kc >> 1) << 6, cc = ((kc & 1) << 2) + (lane >> 4);
            int n0 = wn_s + (lane & 15);
            int n1 = n0 + 16;
            half8 bf0 = *(const half8*)&Ks[cur][(n0 << 8) + kb + ((cc ^ (n0 & 7)) << 3)];
            half8 bf1 = *(const half8*)&Ks[cur][(n1 << 8) + kb + ((cc ^ (n1 & 7)) << 3)];
            accs[0] = __builtin_amdgcn_mfma_f32_16x16x32_f16(qf[kc], bf0, accs[0], 0, 0, 0);
            accs[1] = __builtin_amdgcn_mfma_f32_16x16x32_f16(qf[kc], bf1, accs[1], 0, 0, 0);
        }

        // ---- P = exp(S) (mask -> 1), bf16 to swizzled LDS, accumulate l ----
        {
            int qrow = wm_s + ((lane >> 4) << 2);
            #pragma unroll
            for (int ni = 0; ni < 2; ++ni) {
                int kl = wn_s + (ni << 4) + (lane & 15);
                #pragma unroll
                for (int r = 0; r < 4; ++r) {
                    int q = qrow + r;
                    float p = mv[r] ? __expf(accs[ni][r]) : 1.0f;
                    Ps[(q << 6) + ((((kl >> 3) ^ (q & 7)) << 3)) + (kl & 7)] = f2bf(p);
                    lacc[r] += p;
                }
            }
        }
        __syncthreads();   // barrier B: P published; V(kt+1) drained

        if (kt < 15) stageK(cur ^ 1, kt + 1);   // covered by PV phase

        // ---- O += P . V (wave tile 32q x 64d) ----
        #pragma unroll
        for (int kc2 = 0; kc2 < 2; ++kc2) {
            s16x8 pa[2], vb[4];
            int cc = (kc2 << 2) + (lane >> 4);
            #pragma unroll
            for (int mi = 0; mi < 2; ++mi) {
                int m = wm_v + (mi << 4) + (lane & 15);
                pa[mi] = *(const s16x8*)&Ps[(m << 6) + ((cc ^ (m & 7)) << 3)];
            }
            #pragma unroll
            for (int ni = 0; ni < 4; ++ni) {
                int n = wn_v + (ni << 4) + (lane & 15);
                vb[ni] = *(const s16x8*)&Vs[cur][(n << 6) + ((cc ^ (n & 7)) << 3)];
            }
            #pragma unroll
            for (int mi = 0; mi < 2; ++mi)
                #pragma unroll
                for (int ni = 0; ni < 4; ++ni)
                    o_acc[mi][ni] = __builtin_amdgcn_mfma_f32_16x16x32_bf16(
                        pa[mi], vb[ni], o_acc[mi][ni], 0, 0, 0);
        }
        __syncthreads();   // barrier A: PV done (Ps free); K(kt+1) drained
    }

    // ---- l reduction (Ps memory reused as lred[128][2]) ----
    #pragma unroll
    for (int r = 0; r < 4; ++r) {
        float v = lacc[r];
        v += __shfl_xor(v, 1);
        v += __shfl_xor(v, 2);
        v += __shfl_xor(v, 4);
        v += __shfl_xor(v, 8);
        if ((lane & 15) == 0)
            lredp[((wm_s + ((lane >> 4) << 2) + r) << 1) + (w & 1)] = v;
    }
    __syncthreads();

    // ---- epilogue: Out = O / l ----
    #pragma unroll
    for (int mi = 0; mi < 2; ++mi) {
        #pragma unroll
        for (int rr = 0; rr < 4; ++rr) {
            int q = wm_v + (mi << 4) + ((lane >> 4) << 2) + rr;
            float inv = 1.0f / (lredp[q << 1] + lredp[(q << 1) + 1]);
            #pragma unroll
            for (int ni = 0; ni < 4; ++ni) {
                int d = wn_v + (ni << 4) + (lane & 15);
                Out[((bL + q0 + q) << 8) + d] = o_acc[mi][ni][rr] * inv;
            }
        }
    }
}

extern "C" void kernel_launch(void* const* d_in, const int* in_sizes, int n_in,
                              void* d_out, int out_size, void* d_ws, size_t ws_size,
                              hipStream_t stream) {
    const float* rq = (const float*)d_in[0];
    const float* rk = (const float*)d_in[1];
    const float* rv = (const float*)d_in[2];
    const int*   vm = (const int*)d_in[3];
    const float* WQ = (const float*)d_in[4];
    const float* WK = (const float*)d_in[5];
    const float* WV = (const float*)d_in[6];
    float* out = (float*)d_out;

    char* ws = (char*)d_ws;
    unsigned short* Qh = (unsigned short*)(ws);                          // 16 MB fp16 [b*L][D]
    unsigned short* Kh = (unsigned short*)(ws + ((size_t)16 << 20));     // 16 MB fp16 [b*L][D]
    unsigned short* Vt = (unsigned short*)(ws + ((size_t)32 << 20));     // 16 MB bf16 [b][D][LK]
    unsigned short* Wt = (unsigned short*)(ws + ((size_t)48 << 20));     // 384 KB fp16 [3][256][256]

    dim3 wg(4, 4, 3);
    wprep_kernel<<<wg, 256, 0, stream>>>(WQ, WK, WV, Wt);

    dim3 pg(256, 2, 3);
    proj_mfma_kernel<<<pg, 256, 0, stream>>>(rq, rk, rv, Wt, Qh, Kh, Vt);

    fused_attn_kernel<<<256, 1024, 0, stream>>>(Qh, Kh, Vt, vm, out);
}

// Round 12
// 89.687 us; speedup vs baseline: 1.3072x; 1.0203x over previous
//
#include <hip/hip_runtime.h>
#include <hip/hip_bf16.h>
#include <math.h>

#define B_ 32
#define L_ 1024
#define D_ 256

typedef _Float16 half8 __attribute__((ext_vector_type(8)));
typedef __fp16   fp16x2 __attribute__((ext_vector_type(2)));
typedef short    s16x8 __attribute__((ext_vector_type(8)));
typedef float    f32x4 __attribute__((ext_vector_type(4)));

typedef __attribute__((address_space(3))) unsigned int lds_u32;
typedef __attribute__((address_space(1))) unsigned int gbl_u32;

__device__ __forceinline__ void gl_lds16(const void* g, void* l) {
    __builtin_amdgcn_global_load_lds((gbl_u32*)g, (lds_u32*)l, 16, 0, 0);
}

__device__ __forceinline__ unsigned short f2bf(float x) {
    unsigned u = __float_as_uint(x);
    u += 0x7FFFu + ((u >> 16) & 1u);
    return (unsigned short)(u >> 16);
}

__device__ __forceinline__ unsigned short f2h(float x) {
    _Float16 h = (_Float16)x;
    unsigned short u;
    __builtin_memcpy(&u, &h, 2);
    return u;
}

__device__ __forceinline__ unsigned pkrtz(float a, float b) {
    fp16x2 v = __builtin_amdgcn_cvt_pkrtz(a, b);
    unsigned u;
    __builtin_memcpy(&u, &v, 4);
    return u;
}

// ---------------------------------------------------------------------------
// W-prep: Wt[z][n][k] = fp16(W[z][k][n]) via LDS 64x64 tile transpose.
// ---------------------------------------------------------------------------
__global__ __launch_bounds__(256) void wprep_kernel(
    const float* __restrict__ W0, const float* __restrict__ W1,
    const float* __restrict__ W2, unsigned short* __restrict__ Wt)
{
    const int z = blockIdx.z;
    const float* __restrict__ W = (z == 0) ? W0 : (z == 1) ? W1 : W2;
    __shared__ unsigned short T[64][72];
    const int k0 = blockIdx.x << 6, n0 = blockIdx.y << 6;
    const int t = threadIdx.x;
    const int r = t >> 2, c0 = (t & 3) << 4;
    #pragma unroll
    for (int j = 0; j < 16; j += 4) {
        float4 w4 = *(const float4*)(W + (size_t)(k0 + r) * 256 + n0 + c0 + j);
        T[c0 + j + 0][r] = f2h(w4.x);
        T[c0 + j + 1][r] = f2h(w4.y);
        T[c0 + j + 2][r] = f2h(w4.z);
        T[c0 + j + 3][r] = f2h(w4.w);
    }
    __syncthreads();
    const int n = t >> 2, kc = (t & 3) << 4;
    unsigned short* dst = Wt + ((size_t)z << 16) + (size_t)(n0 + n) * 256 + k0 + kc;
    *(uint4*)(dst + 0) = *(const uint4*)&T[n][kc + 0];
    *(uint4*)(dst + 8) = *(const uint4*)&T[n][kc + 8];
}

// ---------------------------------------------------------------------------
// Projection GEMM, fp16 MFMA 16x16x32. C[M=32768,256] = A @ W.
// BM=128, BN=128 (grid y=2), BK=32, 4 waves 2x2, wave tile 64x64.
// Double-buffered 32 KB LDS -> 4 blocks/CU (16 waves) for memory-latency
// hiding. A path T14-split (global->regs one iter early -> pkrtz -> swizzled
// ds_write). B via gl_lds w/ pre-swizzled source. swz(r)=(r+(r>>2))&3.
// z<2: store fp16 row-major. z=2: LDS-transpose -> Vt bf16 [b][d][k].
// ---------------------------------------------------------------------------
__global__ __launch_bounds__(256, 4) void proj_mfma_kernel(
    const float* __restrict__ A0, const float* __restrict__ A1,
    const float* __restrict__ A2, const unsigned short* __restrict__ Wt,
    unsigned short* __restrict__ Qh, unsigned short* __restrict__ Kh,
    unsigned short* __restrict__ Vt)
{
    __shared__ unsigned short SMEM[18432];   // 36 KB (also fits z=2 transpose)
    unsigned short* Asm = SMEM;              // [buf][128*32], buf stride 4096
    unsigned short* Bsm = SMEM + 8192;       // [buf][128*32]

    const int z = blockIdx.z;
    const float* __restrict__ A = (z == 0) ? A0 : (z == 1) ? A1 : A2;
    const int bm = blockIdx.x << 7, bn = blockIdx.y << 7;
    const int t = threadIdx.x, lane = t & 63, w = t >> 6;
    const int wm = (w >> 1) << 6, wn = (w & 1) << 6;

    const float* __restrict__ Ag = A + (size_t)bm * 256;
    const unsigned short* __restrict__ Bg = Wt + ((size_t)z << 16) + (size_t)bn * 256;

    f32x4 acc[4][4];
    const f32x4 z4 = {0.f, 0.f, 0.f, 0.f};
    #pragma unroll
    for (int mi = 0; mi < 4; ++mi)
        #pragma unroll
        for (int ni = 0; ni < 4; ++ni) acc[mi][ni] = z4;

    // per-thread A ownership: row r = t>>1 (0..127), col-half ch = t&1
    const int ar = t >> 1, ach = t & 1;
    float4 a_reg[4];   // 16 floats = half a row's K-slice, in flight

    auto loadA = [&](int it) {
        #pragma unroll
        for (int i = 0; i < 4; ++i)
            a_reg[i] = *(const float4*)(Ag + (size_t)ar * 256 + (it << 5) + (ach << 4) + (i << 2));
    };
    auto writeA = [&](int buf) {
        unsigned h[8];
        #pragma unroll
        for (int i = 0; i < 4; ++i) {
            h[2 * i]     = pkrtz(a_reg[i].x, a_reg[i].y);
            h[2 * i + 1] = pkrtz(a_reg[i].z, a_reg[i].w);
        }
        int swz = (ar + (ar >> 2)) & 3;
        #pragma unroll
        for (int jj = 0; jj < 2; ++jj) {
            int cs = ((ach << 1) + jj) ^ swz;
            uint2 d0; d0.x = h[4 * jj + 0]; d0.y = h[4 * jj + 1];
            uint2 d1; d1.x = h[4 * jj + 2]; d1.y = h[4 * jj + 3];
            *(uint2*)&Asm[(buf << 12) + (ar << 5) + (cs << 3) + 0] = d0;
            *(uint2*)&Asm[(buf << 12) + (ar << 5) + (cs << 3) + 4] = d1;
        }
    };
    auto stageB = [&](int buf, int it) {
        #pragma unroll
        for (int i = 0; i < 2; ++i) {
            int o = (i << 8) + t;           // 0..511 chunks of 8 halves
            int r = o >> 2, c = o & 3;
            int cs = c ^ ((r + (r >> 2)) & 3);
            gl_lds16(Bg + (size_t)r * 256 + (it << 5) + (cs << 3),
                     &Bsm[(buf << 12) + (o << 3)]);
        }
    };
    auto compute = [&](int buf) {
        half8 af[4], bfr[4];
        const int cc = lane >> 4;
        #pragma unroll
        for (int mi = 0; mi < 4; ++mi) {
            int m = wm + (mi << 4) + (lane & 15);
            int cs = cc ^ ((m + (m >> 2)) & 3);
            af[mi] = *(const half8*)&Asm[(buf << 12) + (m << 5) + (cs << 3)];
        }
        #pragma unroll
        for (int ni = 0; ni < 4; ++ni) {
            int n = wn + (ni << 4) + (lane & 15);
            int cs = cc ^ ((n + (n >> 2)) & 3);
            bfr[ni] = *(const half8*)&Bsm[(buf << 12) + (n << 5) + (cs << 3)];
        }
        #pragma unroll
        for (int mi = 0; mi < 4; ++mi)
            #pragma unroll
            for (int ni = 0; ni < 4; ++ni)
                acc[mi][ni] = __builtin_amdgcn_mfma_f32_16x16x32_f16(
                    af[mi], bfr[ni], acc[mi][ni], 0, 0, 0);
    };

    loadA(0);
    writeA(0);
    stageB(0, 0);
    loadA(1);
    __syncthreads();

    for (int it = 0; it < 8; ++it) {
        const int buf = it & 1;
        if (it < 7) {
            stageB(buf ^ 1, it + 1);
            writeA(buf ^ 1);              // a_reg(it+1) loaded one iter ago
            if (it < 6) loadA(it + 2);    // in flight across barrier+compute
        }
        compute(buf);
        __syncthreads();
    }

    if (z < 2) {
        unsigned short* __restrict__ C = (z == 0) ? Qh : Kh;
        #pragma unroll
        for (int mi = 0; mi < 4; ++mi) {
            int q = bm + wm + (mi << 4) + ((lane >> 4) << 2);
            #pragma unroll
            for (int ni = 0; ni < 4; ++ni) {
                int col = bn + wn + (ni << 4) + (lane & 15);
                #pragma unroll
                for (int r = 0; r < 4; ++r)
                    C[(size_t)(q + r) * 256 + col] = f2h(acc[mi][ni][r]);
            }
        }
    } else {
        __syncthreads();
        unsigned short (*Tt)[144] = (unsigned short(*)[144])SMEM;  // 128x144 = 36 KB
        #pragma unroll
        for (int mi = 0; mi < 4; ++mi) {
            #pragma unroll
            for (int ni = 0; ni < 4; ++ni) {
                int n  = wn + (ni << 4) + (lane & 15);
                int m0 = wm + (mi << 4) + ((lane >> 4) << 2);
                ushort4 v;
                v.x = f2bf(acc[mi][ni][0]);
                v.y = f2bf(acc[mi][ni][1]);
                v.z = f2bf(acc[mi][ni][2]);
                v.w = f2bf(acc[mi][ni][3]);
                *(ushort4*)&Tt[n][m0] = v;
            }
        }
        __syncthreads();
        const int bb = bm >> 10, kin = bm & 1023;
        const int dr = t >> 1, cb = (t & 1) << 6;
        unsigned short* dst = Vt + ((size_t)bb * 256 + bn + dr) * 1024 + kin + cb;
        #pragma unroll
        for (int j = 0; j < 8; ++j)
            *(uint4*)(dst + (j << 3)) = *(const uint4*)&Tt[dr][cb + (j << 3)];
    }
}

// ---------------------------------------------------------------------------
// Fused flash attention, QBLK=128, KB=64, 256 blocks (1/CU), 1024 threads
// (16 waves = 4 waves/SIMD). Double-buffered K [2][64][256] + V [2][256][64]
// + XOR-swizzled Ps [128][64] = 144 KB LDS. Per k-tile:
//   [stageV(kt+1) | S(kt) on Ks[cur] | exp/P | barrier B |
//    stageK(kt+1) | PV(kt) on Vs[cur],Ps | barrier A]
// S waves 8(M)x2(N): 16q x 32k, Q in regs. PV waves 4(M)x4(N): 32q x 64d.
// XCD decode: 8 q-tiles of a batch share f%8 -> 4 batches/XCD L2-resident.
// ---------------------------------------------------------------------------
__global__ __launch_bounds__(1024, 4) void fused_attn_kernel(
    const unsigned short* __restrict__ Qh, const unsigned short* __restrict__ Kh,
    const unsigned short* __restrict__ Vt, const int* __restrict__ mask,
    float* __restrict__ Out)
{
    __shared__ unsigned short Ks[2][16384];  // [64][256] halves x2, 64 KB
    __shared__ unsigned short Vs[2][16384];  // [256][64] halves x2, 64 KB
    __shared__ unsigned short Ps[128 * 64];  // 16 KB bf16, XOR-swizzled chunks
    float* lredp = (float*)Ps;               // overlay, used after the loop

    // XCD-aware decode: f = xcd + 8*qtile + 64*batchgroup
    const int f  = blockIdx.x;
    const int b  = (f & 7) + ((f >> 6) << 3);
    const int q0 = ((f >> 3) & 7) << 7;
    const size_t bL = (size_t)b * L_;
    const int t = threadIdx.x, lane = t & 63, w = t >> 6;
    const int wm_s = (w >> 1) << 4, wn_s = (w & 1) << 5;   // S: 8x2, 16q x 32k
    const int wm_v = (w >> 2) << 5, wn_v = (w & 3) << 6;   // PV: 4x4, 32q x 64d

    const unsigned short* __restrict__ Kb = Kh + (bL << 8);
    const unsigned short* __restrict__ Vb = Vt + (bL << 8);

    auto stageK = [&](int buf, int kt) {
        #pragma unroll
        for (int i = 0; i < 2; ++i) {
            int o = (i << 10) + t;           // 0..2047 chunks of 8 halves
            int r = o >> 5, c = o & 31;
            int cs = (c & 24) | ((c & 7) ^ (r & 7));
            gl_lds16(Kb + (size_t)((kt << 6) + r) * 256 + (cs << 3), &Ks[buf][o << 3]);
        }
    };
    auto stageV = [&](int buf, int kt) {
        #pragma unroll
        for (int i = 0; i < 2; ++i) {
            int o = (i << 10) + t;           // 0..2047
            int d = o >> 3, c = o & 7;
            int cs = c ^ (d & 7);
            gl_lds16(Vb + ((size_t)d << 10) + (kt << 6) + (cs << 3), &Vs[buf][o << 3]);
        }
    };

    // prologue: stage tile 0, load Q fragments + mask into registers
    stageK(0, 0);
    stageV(0, 0);

    half8 qf[8];
    {
        int m = wm_s + (lane & 15);
        const unsigned short* qp = Qh + ((bL + q0 + m) << 8) + ((lane >> 4) << 3);
        #pragma unroll
        for (int kc = 0; kc < 8; ++kc)
            qf[kc] = *(const half8*)(qp + (kc << 5));
    }
    int mv[4];
    {
        int qrow = wm_s + ((lane >> 4) << 2);
        #pragma unroll
        for (int r = 0; r < 4; ++r) mv[r] = mask[bL + q0 + qrow + r];
    }

    f32x4 o_acc[2][4];
    const f32x4 z4 = {0.f, 0.f, 0.f, 0.f};
    #pragma unroll
    for (int mi = 0; mi < 2; ++mi)
        #pragma unroll
        for (int ni = 0; ni < 4; ++ni) o_acc[mi][ni] = z4;
    float lacc[4] = {};

    __syncthreads();   // tile 0 staged (vmcnt drained)

    for (int kt = 0; kt < 16; ++kt) {
        const int cur = kt & 1;
        if (kt < 15) stageV(cur ^ 1, kt + 1);   // covered by S-phase

        // ---- S = Q . K^T (wave tile 16q x 32k), Q in regs ----
        f32x4 accs[2];
        accs[0] = z4; accs[1] = z4;
        #pragma unroll
        for (int kc = 0; kc < 8; ++kc) {
            int kb = (kc >> 1) << 6, cc = ((kc & 1) << 2) + (lane >> 4);
            int n0 = wn_s + (lane & 15);
            int n1 = n0 + 16;
            half8 bf0 = *(const half8*)&Ks[cur][(n0 << 8) + kb + ((cc ^ (n0 & 7)) << 3)];
            half8 bf1 = *(const half8*)&Ks[cur][(n1 << 8) + kb + ((cc ^ (n1 & 7)) << 3)];
            accs[0] = __builtin_amdgcn_mfma_f32_16x16x32_f16(qf[kc], bf0, accs[0], 0, 0, 0);
            accs[1] = __builtin_amdgcn_mfma_f32_16x16x32_f16(qf[kc], bf1, accs[1], 0, 0, 0);
        }

        // ---- P = exp(S) (mask -> 1), bf16 to swizzled LDS, accumulate l ----
        {
            int qrow = wm_s + ((lane >> 4) << 2);
            #pragma unroll
            for (int ni = 0; ni < 2; ++ni) {
                int kl = wn_s + (ni << 4) + (lane & 15);
                #pragma unroll
                for (int r = 0; r < 4; ++r) {
                    int q = qrow + r;
                    float p = mv[r] ? __expf(accs[ni][r]) : 1.0f;
                    Ps[(q << 6) + ((((kl >> 3) ^ (q & 7)) << 3)) + (kl & 7)] = f2bf(p);
                    lacc[r] += p;
                }
            }
        }
        __syncthreads();   // barrier B: P published; V(kt+1) drained

        if (kt < 15) stageK(cur ^ 1, kt + 1);   // covered by PV phase

        // ---- O += P . V (wave tile 32q x 64d) ----
        #pragma unroll
        for (int kc2 = 0; kc2 < 2; ++kc2) {
            s16x8 pa[2], vb[4];
            int cc = (kc2 << 2) + (lane >> 4);
            #pragma unroll
            for (int mi = 0; mi < 2; ++mi) {
                int m = wm_v + (mi << 4) + (lane & 15);
                pa[mi] = *(const s16x8*)&Ps[(m << 6) + ((cc ^ (m & 7)) << 3)];
            }
            #pragma unroll
            for (int ni = 0; ni < 4; ++ni) {
                int n = wn_v + (ni << 4) + (lane & 15);
                vb[ni] = *(const s16x8*)&Vs[cur][(n << 6) + ((cc ^ (n & 7)) << 3)];
            }
            #pragma unroll
            for (int mi = 0; mi < 2; ++mi)
                #pragma unroll
                for (int ni = 0; ni < 4; ++ni)
                    o_acc[mi][ni] = __builtin_amdgcn_mfma_f32_16x16x32_bf16(
                        pa[mi], vb[ni], o_acc[mi][ni], 0, 0, 0);
        }
        __syncthreads();   // barrier A: PV done (Ps free); K(kt+1) drained
    }

    // ---- l reduction (Ps memory reused as lred[128][2]) ----
    #pragma unroll
    for (int r = 0; r < 4; ++r) {
        float v = lacc[r];
        v += __shfl_xor(v, 1);
        v += __shfl_xor(v, 2);
        v += __shfl_xor(v, 4);
        v += __shfl_xor(v, 8);
        if ((lane & 15) == 0)
            lredp[((wm_s + ((lane >> 4) << 2) + r) << 1) + (w & 1)] = v;
    }
    __syncthreads();

    // ---- epilogue: Out = O / l ----
    #pragma unroll
    for (int mi = 0; mi < 2; ++mi) {
        #pragma unroll
        for (int rr = 0; rr < 4; ++rr) {
            int q = wm_v + (mi << 4) + ((lane >> 4) << 2) + rr;
            float inv = 1.0f / (lredp[q << 1] + lredp[(q << 1) + 1]);
            #pragma unroll
            for (int ni = 0; ni < 4; ++ni) {
                int d = wn_v + (ni << 4) + (lane & 15);
                Out[((bL + q0 + q) << 8) + d] = o_acc[mi][ni][rr] * inv;
            }
        }
    }
}

extern "C" void kernel_launch(void* const* d_in, const int* in_sizes, int n_in,
                              void* d_out, int out_size, void* d_ws, size_t ws_size,
                              hipStream_t stream) {
    const float* rq = (const float*)d_in[0];
    const float* rk = (const float*)d_in[1];
    const float* rv = (const float*)d_in[2];
    const int*   vm = (const int*)d_in[3];
    const float* WQ = (const float*)d_in[4];
    const float* WK = (const float*)d_in[5];
    const float* WV = (const float*)d_in[6];
    float* out = (float*)d_out;

    char* ws = (char*)d_ws;
    unsigned short* Qh = (unsigned short*)(ws);                          // 16 MB fp16 [b*L][D]
    unsigned short* Kh = (unsigned short*)(ws + ((size_t)16 << 20));     // 16 MB fp16 [b*L][D]
    unsigned short* Vt = (unsigned short*)(ws + ((size_t)32 << 20));     // 16 MB bf16 [b][D][LK]
    unsigned short* Wt = (unsigned short*)(ws + ((size_t)48 << 20));     // 384 KB fp16 [3][256][256]

    dim3 wg(4, 4, 3);
    wprep_kernel<<<wg, 256, 0, stream>>>(WQ, WK, WV, Wt);

    dim3 pg(256, 2, 3);
    proj_mfma_kernel<<<pg, 256, 0, stream>>>(rq, rk, rv, Wt, Qh, Kh, Vt);

    fused_attn_kernel<<<256, 1024, 0, stream>>>(Qh, Kh, Vt, vm, out);
}